// Round 13
// baseline (695.342 us; speedup 1.0000x reference)
//
#include <hip/hip_runtime.h>

#define N_NODES 100000
#define E_EDGES 300000
#define N_GRAPHS 2048

typedef float  floatx4 __attribute__((ext_vector_type(4)));
typedef short  shortx8 __attribute__((ext_vector_type(8)));

__device__ __forceinline__ float bf2f(unsigned short u) {
  return __uint_as_float(((unsigned int)u) << 16);
}
__device__ __forceinline__ unsigned short f2bf(float f) {
  unsigned int u = __float_as_uint(f);
  u += 0x7FFFu + ((u >> 16) & 1u);
  return (unsigned short)(u >> 16);
}

// async global->LDS, 16B per lane; lds base wave-uniform, dst = base+lane*16 (m104)
__device__ __forceinline__ void cp16(const void* g, void* l) {
  __builtin_amdgcn_global_load_lds(
      (const __attribute__((address_space(1))) unsigned int*)g,
      (__attribute__((address_space(3))) unsigned int*)l, 16, 0, 0);
}

// ---------------- embed: H[n,128] = bf16(X[n,40] @ We[40,128] + be) ----------
__global__ __launch_bounds__(128)
void embed_kernel(const float* __restrict__ X, const float* __restrict__ W,
                  const float* __restrict__ b, unsigned short* __restrict__ H) {
  __shared__ float Ws[40 * 128];
  __shared__ float Xs[16 * 40];
  const int t = threadIdx.x;
  const int nb = blockIdx.x * 16;
  for (int i = t; i < 40 * 128; i += 128) Ws[i] = W[i];
  for (int i = t; i < 16 * 40; i += 128) Xs[i] = X[(size_t)nb * 40 + i];
  __syncthreads();
  const float bias = b[t];
  for (int n = 0; n < 16; n++) {
    float acc = bias;
#pragma unroll
    for (int k = 0; k < 40; k++) acc = fmaf(Xs[n * 40 + k], Ws[k * 128 + t], acc);
    H[(size_t)(nb + n) * 128 + t] = f2bf(acc);
  }
}

// -------- batched W[k,n] fp32 -> Wt[n,k] bf16 (32x32 LDS tiles, 5 jobs) ------
struct WtJobs {
  const float* W[5];
  unsigned short* Wt[5];
  int K[5];
  int N[5];
};

__global__ __launch_bounds__(256)
void wt5_kernel(WtJobs j) {
  __shared__ unsigned short tile[32][33];
  const int z = blockIdx.z;
  const int K = j.K[z], N = j.N[z];
  const int kb = blockIdx.x * 32, nb = blockIdx.y * 32;
  if (kb >= K || nb >= N) return;
  const float* W = j.W[z];
  unsigned short* Wt = j.Wt[z];
  const int tx = threadIdx.x & 31, ty = threadIdx.x >> 5;
  for (int r = ty; r < 32; r += 8)
    tile[r][tx] = f2bf(W[(size_t)(kb + r) * N + nb + tx]);
  __syncthreads();
  for (int r = ty; r < 32; r += 8)
    Wt[(size_t)(nb + r) * K + kb + tx] = tile[tx][r];
}

// ---- w2v[k] = sum_n W2_2[k,n]*wtask[n]; c2 = sum_n b2[n]*wtask[n] -----------
__global__ __launch_bounds__(256)
void w2v_kernel(const float* __restrict__ W2, const float* __restrict__ b2,
                const float* __restrict__ wt, float* __restrict__ w2v,
                float* __restrict__ c2) {
  int k = blockIdx.x * 256 + threadIdx.x;
  if (k < 512) {
    float s = 0.f;
    for (int n = 0; n < 512; n++) s = fmaf(W2[(size_t)k * 512 + n], wt[n], s);
    w2v[k] = s;
  }
  if (blockIdx.x == 0 && threadIdx.x == 0) {
    float s = 0.f;
    for (int n = 0; n < 512; n++) s = fmaf(b2[n], wt[n], s);
    *c2 = s;
  }
}

__global__ __launch_bounds__(256)
void init_nd_kernel(float* __restrict__ nd, const float* __restrict__ c2) {
  int i = blockIdx.x * 256 + threadIdx.x;
  if (i < N_NODES) nd[i] = *c2;
}

// ---------------- CSR build: zero, histogram, scan, fill ---------------------
__global__ __launch_bounds__(256)
void zero_kernel(int* __restrict__ p, int n) {
  int i = blockIdx.x * 256 + threadIdx.x;
  if (i < n) p[i] = 0;
}

__global__ __launch_bounds__(256)
void hist_kernel(const int* __restrict__ ei, int* __restrict__ deg) {
  int e = blockIdx.x * 256 + threadIdx.x;
  if (e < E_EDGES) atomicAdd(&deg[ei[E_EDGES + e]], 1);
}

__global__ __launch_bounds__(256)
void scan_blk_kernel(const int* __restrict__ in, int* __restrict__ out,
                     int* __restrict__ blk_sums, int n_in, int n_out) {
  __shared__ int sm[256];
  const int t = threadIdx.x;
  const int base = blockIdx.x * 1024 + t * 4;
  int d0 = (base + 0 < n_in) ? in[base + 0] : 0;
  int d1 = (base + 1 < n_in) ? in[base + 1] : 0;
  int d2 = (base + 2 < n_in) ? in[base + 2] : 0;
  int d3 = (base + 3 < n_in) ? in[base + 3] : 0;
  int s = d0 + d1 + d2 + d3;
  sm[t] = s;
  __syncthreads();
  for (int off = 1; off < 256; off <<= 1) {
    int v = (t >= off) ? sm[t - off] : 0;
    __syncthreads();
    sm[t] += v;
    __syncthreads();
  }
  int excl = sm[t] - s;
  if (base + 0 < n_out) out[base + 0] = excl;
  if (base + 1 < n_out) out[base + 1] = excl + d0;
  if (base + 2 < n_out) out[base + 2] = excl + d0 + d1;
  if (base + 3 < n_out) out[base + 3] = excl + d0 + d1 + d2;
  if (t == 255 && blk_sums) blk_sums[blockIdx.x] = sm[255];
}

__global__ __launch_bounds__(256)
void scan_fix_kernel(int* __restrict__ row_ptr, const int* __restrict__ blk_off,
                     int* __restrict__ cursor) {
  int i = blockIdx.x * 256 + threadIdx.x;
  if (i <= N_NODES) {
    int v = row_ptr[i] + blk_off[i >> 10];
    row_ptr[i] = v;
    if (i < N_NODES) cursor[i] = v;
  }
}

__global__ __launch_bounds__(256)
void fill_kernel(const int* __restrict__ ei, int* __restrict__ cursor,
                 int* __restrict__ csr_src) {
  int e = blockIdx.x * 256 + threadIdx.x;
  if (e < E_EDGES) {
    int d = ei[E_EDGES + e];
    int slot = atomicAdd(&cursor[d], 1);
    csr_src[slot] = ei[e];
  }
}

// ------- gather: Z[d] = bf16((1+eps)*H[d] + sum_{s->d} H[s]), fp32 accum -----
// (standalone version, used only for layer 2 feeding the MODE-3 GEMM)
template <int NV>  // NV bf16 feats per lane, D = NV*64
__global__ __launch_bounds__(256)
void gather_kernel(const unsigned short* __restrict__ H, unsigned short* __restrict__ Z,
                   const int* __restrict__ row_ptr, const int* __restrict__ csr,
                   const float* __restrict__ eps, int l) {
  const int D = NV * 64;
  const int node = blockIdx.x * 4 + (threadIdx.x >> 6);
  const int lane = threadIdx.x & 63;
  const float sc = 1.0f + eps[l];
  const unsigned short* hp0 = H + (size_t)node * D + lane * NV;
  float acc[NV];
  if constexpr (NV == 4) {
    uint2 hv = *(const uint2*)hp0;
    acc[0] = sc * bf2f((unsigned short)(hv.x & 0xFFFF));
    acc[1] = sc * bf2f((unsigned short)(hv.x >> 16));
    acc[2] = sc * bf2f((unsigned short)(hv.y & 0xFFFF));
    acc[3] = sc * bf2f((unsigned short)(hv.y >> 16));
  } else {
    unsigned int hv = *(const unsigned int*)hp0;
    acc[0] = sc * bf2f((unsigned short)(hv & 0xFFFF));
    acc[1] = sc * bf2f((unsigned short)(hv >> 16));
  }
  const int e0 = row_ptr[node];
  const int e1 = row_ptr[node + 1];
  int e = e0;
  for (; e + 2 <= e1; e += 2) {
    int s0 = csr[e], s1 = csr[e + 1];
    const unsigned short* p0 = H + (size_t)s0 * D + lane * NV;
    const unsigned short* p1 = H + (size_t)s1 * D + lane * NV;
    if constexpr (NV == 4) {
      uint2 a = *(const uint2*)p0;
      uint2 b = *(const uint2*)p1;
      acc[0] += bf2f((unsigned short)(a.x & 0xFFFF)) + bf2f((unsigned short)(b.x & 0xFFFF));
      acc[1] += bf2f((unsigned short)(a.x >> 16))    + bf2f((unsigned short)(b.x >> 16));
      acc[2] += bf2f((unsigned short)(a.y & 0xFFFF)) + bf2f((unsigned short)(b.y & 0xFFFF));
      acc[3] += bf2f((unsigned short)(a.y >> 16))    + bf2f((unsigned short)(b.y >> 16));
    } else {
      unsigned int a = *(const unsigned int*)p0;
      unsigned int b = *(const unsigned int*)p1;
      acc[0] += bf2f((unsigned short)(a & 0xFFFF)) + bf2f((unsigned short)(b & 0xFFFF));
      acc[1] += bf2f((unsigned short)(a >> 16))    + bf2f((unsigned short)(b >> 16));
    }
  }
  if (e < e1) {
    int s0 = csr[e];
    const unsigned short* p0 = H + (size_t)s0 * D + lane * NV;
    if constexpr (NV == 4) {
      uint2 a = *(const uint2*)p0;
      acc[0] += bf2f((unsigned short)(a.x & 0xFFFF));
      acc[1] += bf2f((unsigned short)(a.x >> 16));
      acc[2] += bf2f((unsigned short)(a.y & 0xFFFF));
      acc[3] += bf2f((unsigned short)(a.y >> 16));
    } else {
      unsigned int a = *(const unsigned int*)p0;
      acc[0] += bf2f((unsigned short)(a & 0xFFFF));
      acc[1] += bf2f((unsigned short)(a >> 16));
    }
  }
  unsigned short* zp = Z + (size_t)node * D + lane * NV;
  if constexpr (NV == 4) {
    unsigned short z[4] = {f2bf(acc[0]), f2bf(acc[1]), f2bf(acc[2]), f2bf(acc[3])};
    *(uint2*)zp = *(uint2*)z;
  } else {
    unsigned short z[2] = {f2bf(acc[0]), f2bf(acc[1])};
    *(unsigned int*)zp = *(unsigned int*)z;
  }
}

// ---- FUSED gather+GEMM1: C = relu((gather(H)) @ Bt^T + bias) ----------------
// Prologue builds the FULL-K A-tile (128 nodes x K bf16) in LDS by CSR gather
// (fp32 accum) -- Z never exists in global memory, and A is staged exactly
// once (no per-round A traffic). K-loop streams Bs slices (BK=64) from the
// L2-resident Wt via cp16. XOR chunk swizzle on As/Bs: phys chunk =
// (cq&~7)|((cq&7)^(row&7)) -> frag reads hit 8 bank-quads, 2-way = free.
// XCD swizzle on block IDs (R11): duplicate gather of the 2nd column block
// hits the same XCD's L2.
template <int K, int NXL>
__global__ __launch_bounds__(256)
void gemm_gather_kernel(const unsigned short* __restrict__ H,
                        const unsigned short* __restrict__ Bt,
                        const float* __restrict__ bias,
                        unsigned short* __restrict__ C,
                        const int* __restrict__ row_ptr,
                        const int* __restrict__ csr,
                        const float* __restrict__ eps, int l,
                        int M, int N) {
  const int g = blockIdx.x;
  const int mblk = ((g >> (3 + NXL)) << 3) | (g & 7);
  const int nblk = (g >> 3) & ((1 << NXL) - 1);
  const int m0 = mblk * 128;
  const int n0 = nblk * 128;
  if (m0 >= M) return;

  __shared__ unsigned short As[128 * K];   // 32 KB (K=128) / 64 KB (K=256)
  __shared__ unsigned short Bs[128 * 64];  // 16 KB slice
  const int tid = threadIdx.x;
  const int lane = tid & 63;
  const int wave = tid >> 6;
  const int wm = (wave & 1) * 64;
  const int wn = (wave >> 1) * 64;
  const int fr = lane & 15;
  const int fq = lane >> 4;
  constexpr int NV = K / 64;

  // ---- prologue: gather rows [wave*32, wave*32+32) into As ----
  const float sc = 1.0f + eps[l];
  for (int rr = 0; rr < 32; rr++) {
    const int r = wave * 32 + rr;
    int node = m0 + r;
    if (node >= M) node = M - 1;  // clamp; C stores guarded by row<M
    const unsigned short* hp = H + (size_t)node * K + lane * NV;
    float acc[NV];
    if constexpr (NV == 4) {
      uint2 hv = *(const uint2*)hp;
      acc[0] = sc * bf2f((unsigned short)(hv.x & 0xFFFF));
      acc[1] = sc * bf2f((unsigned short)(hv.x >> 16));
      acc[2] = sc * bf2f((unsigned short)(hv.y & 0xFFFF));
      acc[3] = sc * bf2f((unsigned short)(hv.y >> 16));
    } else {
      unsigned int hv = *(const unsigned int*)hp;
      acc[0] = sc * bf2f((unsigned short)(hv & 0xFFFF));
      acc[1] = sc * bf2f((unsigned short)(hv >> 16));
    }
    const int e0 = row_ptr[node];
    const int e1 = row_ptr[node + 1];
    int e = e0;
    for (; e + 2 <= e1; e += 2) {
      int s0 = csr[e], s1 = csr[e + 1];
      const unsigned short* p0 = H + (size_t)s0 * K + lane * NV;
      const unsigned short* p1 = H + (size_t)s1 * K + lane * NV;
      if constexpr (NV == 4) {
        uint2 a = *(const uint2*)p0;
        uint2 b = *(const uint2*)p1;
        acc[0] += bf2f((unsigned short)(a.x & 0xFFFF)) + bf2f((unsigned short)(b.x & 0xFFFF));
        acc[1] += bf2f((unsigned short)(a.x >> 16))    + bf2f((unsigned short)(b.x >> 16));
        acc[2] += bf2f((unsigned short)(a.y & 0xFFFF)) + bf2f((unsigned short)(b.y & 0xFFFF));
        acc[3] += bf2f((unsigned short)(a.y >> 16))    + bf2f((unsigned short)(b.y >> 16));
      } else {
        unsigned int a = *(const unsigned int*)p0;
        unsigned int b = *(const unsigned int*)p1;
        acc[0] += bf2f((unsigned short)(a & 0xFFFF)) + bf2f((unsigned short)(b & 0xFFFF));
        acc[1] += bf2f((unsigned short)(a >> 16))    + bf2f((unsigned short)(b >> 16));
      }
    }
    if (e < e1) {
      int s0 = csr[e];
      const unsigned short* p0 = H + (size_t)s0 * K + lane * NV;
      if constexpr (NV == 4) {
        uint2 a = *(const uint2*)p0;
        acc[0] += bf2f((unsigned short)(a.x & 0xFFFF));
        acc[1] += bf2f((unsigned short)(a.x >> 16));
        acc[2] += bf2f((unsigned short)(a.y & 0xFFFF));
        acc[3] += bf2f((unsigned short)(a.y >> 16));
      } else {
        unsigned int a = *(const unsigned int*)p0;
        acc[0] += bf2f((unsigned short)(a & 0xFFFF));
        acc[1] += bf2f((unsigned short)(a >> 16));
      }
    }
    // swizzled As write: chunk cq of row r at phys (cq&~7)|((cq&7)^(r&7))
    if constexpr (NV == 4) {
      int cq = lane >> 1;
      int phys = (cq & ~7) | ((cq & 7) ^ (r & 7));
      unsigned short z[4] = {f2bf(acc[0]), f2bf(acc[1]), f2bf(acc[2]), f2bf(acc[3])};
      *(uint2*)&As[r * K + phys * 8 + (lane & 1) * 4] = *(uint2*)z;
    } else {
      int cq = lane >> 2;
      int phys = (cq & ~7) | ((cq & 7) ^ (r & 7));
      unsigned short z[2] = {f2bf(acc[0]), f2bf(acc[1])};
      *(unsigned int*)&As[r * K + phys * 8 + (lane & 3) * 2] = *(unsigned int*)z;
    }
  }

  // ---- B staging sources (slice of BK=64, swizzle on the global side) ----
  const unsigned short* gB[4];
#pragma unroll
  for (int p = 0; p < 4; p++) {
    int s = p * 256 + tid;
    int row = s >> 3, phys = s & 7;
    int q = phys ^ (row & 7);
    gB[p] = Bt + (size_t)(n0 + row) * K + q * 8;
  }

  floatx4 acc[4][4];
#pragma unroll
  for (int i = 0; i < 4; i++)
#pragma unroll
    for (int j = 0; j < 4; j++) acc[i][j] = (floatx4){0.f, 0.f, 0.f, 0.f};

  // stage Bs round 0 (overlaps with other waves' prologue tail)
#pragma unroll
  for (int p = 0; p < 4; p++)
    cp16(gB[p], &Bs[(p * 256 + wave * 64) * 8]);
  __syncthreads();  // covers As ds_writes + Bs cp16

  constexpr int R = K / 64;
#pragma unroll
  for (int r8 = 0; r8 < R; r8++) {
#pragma unroll
    for (int s0 = 0; s0 < 2; s0++) {
      shortx8 af[4], bf4[4];
#pragma unroll
      for (int i = 0; i < 4; i++) {
        int m = wm + i * 16 + fr;
        af[i] = *(const shortx8*)&As[m * K + (r8 * 8 + ((s0 * 4 + fq) ^ (m & 7))) * 8];
      }
#pragma unroll
      for (int j = 0; j < 4; j++) {
        int n = wn + j * 16 + fr;
        bf4[j] = *(const shortx8*)&Bs[n * 64 + ((s0 * 4 + fq) ^ (n & 7)) * 8];
      }
#pragma unroll
      for (int i = 0; i < 4; i++)
#pragma unroll
        for (int j = 0; j < 4; j++)
          acc[i][j] = __builtin_amdgcn_mfma_f32_16x16x32_bf16(af[i], bf4[j], acc[i][j], 0, 0, 0);
    }
    __syncthreads();
    if (r8 + 1 < R) {
#pragma unroll
      for (int p = 0; p < 4; p++)
        cp16(gB[p] + (r8 + 1) * 64, &Bs[(p * 256 + wave * 64) * 8]);
      __syncthreads();
    }
  }

  // ---- epilogue: relu(acc+bias) via LDS (As reused), 256B-line stores ----
  unsigned short* Cs = As;
#pragma unroll
  for (int j = 0; j < 4; j++) {
    int col = wn + j * 16 + fr;
    float bj = bias[n0 + col];
#pragma unroll
    for (int i = 0; i < 4; i++) {
#pragma unroll
      for (int r = 0; r < 4; r++) {
        int row = wm + i * 16 + fq * 4 + r;
        Cs[row * 128 + col] = f2bf(fmaxf(acc[i][j][r] + bj, 0.f));
      }
    }
  }
  __syncthreads();
  const int rcol = (tid & 15) * 8;
#pragma unroll
  for (int p = 0; p < 8; p++) {
    int row = p * 16 + (tid >> 4);
    int grow = m0 + row;
    if (grow < M) {
      uint4 v = *(const uint4*)&Cs[row * 128 + rcol];
      *(uint4*)&C[(size_t)grow * N + n0 + rcol] = v;
    }
  }
}

// ---- GEMM (R11): act(A @ Bt^T + bias), 128x128 tile, BK=64, 4 waves --------
// XOR swizzle (zero conflicts) + LDS-staged epilogue + XCD block swizzle.
// MODE 0: C = bf16(relu(.)). MODE 3: nodedot[row] += sum relu(.)*w2v[col].
template <int K, int NXL, int MODE>
__global__ __launch_bounds__(256)
void gemm_kernel(const unsigned short* __restrict__ A,
                 const unsigned short* __restrict__ Bt,
                 const float* __restrict__ bias, unsigned short* __restrict__ C,
                 const float* __restrict__ w2v, float* __restrict__ nodedot,
                 int M, int N) {
  const int g = blockIdx.x;
  const int mblk = ((g >> (3 + NXL)) << 3) | (g & 7);
  const int nblk = (g >> 3) & ((1 << NXL) - 1);
  const int m0 = mblk * 128;
  const int n0 = nblk * 128;
  if (m0 >= M) return;

  __shared__ unsigned short smem[2 * 128 * 64];  // 32 KB: As+Bs, reused as C-tile
  unsigned short* As = smem;
  unsigned short* Bs = smem + 128 * 64;
  const int tid = threadIdx.x;
  const int lane = tid & 63;
  const int wave = tid >> 6;
  const int wm = (wave & 1) * 64;
  const int wn = (wave >> 1) * 64;
  const int fr = lane & 15;
  const int fq = lane >> 4;

  floatx4 acc[4][4];
#pragma unroll
  for (int i = 0; i < 4; i++)
#pragma unroll
    for (int j = 0; j < 4; j++) acc[i][j] = (floatx4){0.f, 0.f, 0.f, 0.f};

  const unsigned short* gA[4];
  const unsigned short* gB[4];
  unsigned short* lA[4];
  unsigned short* lB[4];
#pragma unroll
  for (int p = 0; p < 4; p++) {
    int c = p * 256 + wave * 64 + lane;
    int row = c >> 3;
    int q = (c & 7) ^ (row & 7);
    int grA = m0 + row;
    if (grA >= M) grA = M - 1;
    gA[p] = A + (size_t)grA * K + q * 8;
    gB[p] = Bt + (size_t)(n0 + row) * K + q * 8;
    lA[p] = &As[(p * 256 + wave * 64) * 8];
    lB[p] = &Bs[(p * 256 + wave * 64) * 8];
  }

  for (int k0 = 0; k0 < K; k0 += 64) {
#pragma unroll
    for (int p = 0; p < 4; p++) cp16(gA[p] + k0, lA[p]);
#pragma unroll
    for (int p = 0; p < 4; p++) cp16(gB[p] + k0, lB[p]);
    __syncthreads();
#pragma unroll
    for (int s0 = 0; s0 < 2; s0++) {
      shortx8 af[4], bf[4];
#pragma unroll
      for (int i = 0; i < 4; i++)
        af[i] = *(const shortx8*)&As[(wm + i * 16 + fr) * 64 +
                                     (((s0 * 4 + fq) ^ (fr & 7)) * 8)];
#pragma unroll
      for (int j = 0; j < 4; j++)
        bf[j] = *(const shortx8*)&Bs[(wn + j * 16 + fr) * 64 +
                                     (((s0 * 4 + fq) ^ (fr & 7)) * 8)];
#pragma unroll
      for (int i = 0; i < 4; i++)
#pragma unroll
        for (int j = 0; j < 4; j++)
          acc[i][j] = __builtin_amdgcn_mfma_f32_16x16x32_bf16(af[i], bf[j], acc[i][j], 0, 0, 0);
    }
    __syncthreads();
  }

  if (MODE == 3) {
    float wv[4], bj[4];
#pragma unroll
    for (int j = 0; j < 4; j++) {
      int col = n0 + wn + j * 16 + fr;
      wv[j] = w2v[col];
      bj[j] = bias[col];
    }
#pragma unroll
    for (int i = 0; i < 4; i++) {
#pragma unroll
      for (int r = 0; r < 4; r++) {
        float p = 0.f;
#pragma unroll
        for (int j = 0; j < 4; j++) p += fmaxf(acc[i][j][r] + bj[j], 0.f) * wv[j];
#pragma unroll
        for (int off = 1; off < 16; off <<= 1) p += __shfl_xor(p, off);
        if (fr == 0) {
          int row = m0 + wm + i * 16 + fq * 4 + r;
          if (row < M) unsafeAtomicAdd(&nodedot[row], p);
        }
      }
    }
  } else {
    unsigned short* Cs = smem;
#pragma unroll
    for (int j = 0; j < 4; j++) {
      int col = wn + j * 16 + fr;
      float bj = bias[n0 + col];
#pragma unroll
      for (int i = 0; i < 4; i++) {
#pragma unroll
        for (int r = 0; r < 4; r++) {
          int row = wm + i * 16 + fq * 4 + r;
          Cs[row * 128 + col] = f2bf(fmaxf(acc[i][j][r] + bj, 0.f));
        }
      }
    }
    __syncthreads();
    const int rcol = (tid & 15) * 8;
#pragma unroll
    for (int p = 0; p < 8; p++) {
      int row = p * 16 + (tid >> 4);
      int grow = m0 + row;
      if (grow < M) {
        uint4 v = *(const uint4*)&Cs[row * 128 + rcol];
        *(uint4*)&C[(size_t)grow * N + n0 + rcol] = v;
      }
    }
  }
}

// ---------------- readout ----------------------------------------------------
__global__ __launch_bounds__(256)
void init_out_kernel(float* __restrict__ out, const float* __restrict__ b_task) {
  int g = blockIdx.x * 256 + threadIdx.x;
  if (g < N_GRAPHS) out[g] = b_task[0];
}

__global__ __launch_bounds__(256)
void pool_kernel(const float* __restrict__ nodedot, const int* __restrict__ batch,
                 float* __restrict__ out) {
  int t = blockIdx.x * 256 + threadIdx.x;
  int i0 = t * 64;
  if (i0 >= N_NODES) return;
  int i1 = i0 + 64;
  if (i1 > N_NODES) i1 = N_NODES;
  int g = batch[i0];
  float s = 0.f;
  for (int i = i0; i < i1; i++) {
    int gi = batch[i];
    if (gi != g) { unsafeAtomicAdd(&out[g], s); g = gi; s = 0.f; }
    s += nodedot[i];
  }
  unsafeAtomicAdd(&out[g], s);
}

extern "C" void kernel_launch(void* const* d_in, const int* in_sizes, int n_in,
                              void* d_out, int out_size, void* d_ws, size_t ws_size,
                              hipStream_t stream) {
  const float* x       = (const float*)d_in[0];
  const int*   ei      = (const int*)d_in[1];
  const int*   batch   = (const int*)d_in[2];
  const float* W_embed = (const float*)d_in[3];
  const float* b_embed = (const float*)d_in[4];
  const float* eps     = (const float*)d_in[5];
  const float* W1[3] = {(const float*)d_in[6],  (const float*)d_in[10], (const float*)d_in[14]};
  const float* B1[3] = {(const float*)d_in[7],  (const float*)d_in[11], (const float*)d_in[15]};
  const float* W2[3] = {(const float*)d_in[8],  (const float*)d_in[12], (const float*)d_in[16]};
  const float* B2[3] = {(const float*)d_in[9],  (const float*)d_in[13], (const float*)d_in[17]};
  const float* W_task = (const float*)d_in[18];
  const float* b_task = (const float*)d_in[19];
  float* out = (float*)d_out;

  const size_t OFF_RB  = 51200000;
  const size_t OFF_RZ  = 102400000;
  const size_t OFF_AUX = 153600000;
  if (ws_size < OFF_AUX + 4000000) return;
  unsigned short* RH = (unsigned short*)d_ws;
  unsigned short* RB = (unsigned short*)((char*)d_ws + OFF_RB);
  unsigned short* RZ = (unsigned short*)((char*)d_ws + OFF_RZ);
  char* aux = (char*)d_ws + OFF_AUX;
  int* row_ptr  = (int*)(aux);               // 100001 ints
  int* cursor   = (int*)(aux + 400016);      // 100000 ints (also deg histogram)
  int* csr_src  = (int*)(aux + 800016);      // 300000 ints
  int* blk_sums = (int*)(aux + 2000016);     // 98 ints
  int* blk_off  = (int*)(aux + 2000416);     // 98 ints
  float* nodedot = (float*)(aux + 2000816);  // 100000 floats
  unsigned short* WT = (unsigned short*)(aux + 2400832);  // 360448 bf16
  float* w2v = (float*)(aux + 3200832);      // 512 floats
  float* c2  = (float*)(aux + 3202880);      // 1 float
  unsigned short* Wt1[3] = {WT,          WT + 98304,  WT + 229376};
  unsigned short* Wt2[2] = {WT + 32768,  WT + 163840};

  // ---- weight transpose+convert (5 jobs, one dispatch) ----
  WtJobs jobs;
  jobs.W[0] = W1[0]; jobs.Wt[0] = Wt1[0]; jobs.K[0] = 128; jobs.N[0] = 256;
  jobs.W[1] = W2[0]; jobs.Wt[1] = Wt2[0]; jobs.K[1] = 256; jobs.N[1] = 256;
  jobs.W[2] = W1[1]; jobs.Wt[2] = Wt1[1]; jobs.K[2] = 256; jobs.N[2] = 256;
  jobs.W[3] = W2[1]; jobs.Wt[3] = Wt2[1]; jobs.K[3] = 256; jobs.N[3] = 256;
  jobs.W[4] = W1[2]; jobs.Wt[4] = Wt1[2]; jobs.K[4] = 256; jobs.N[4] = 512;
  wt5_kernel<<<dim3(8, 16, 5), 256, 0, stream>>>(jobs);

  // ---- w2v = W2_2 @ w_task; c2 = b2_2 . w_task ----
  w2v_kernel<<<2, 256, 0, stream>>>(W2[2], B2[2], W_task, w2v, c2);

  // ---- CSR build ----
  zero_kernel<<<(N_NODES + 255) / 256, 256, 0, stream>>>(cursor, N_NODES);
  hist_kernel<<<(E_EDGES + 255) / 256, 256, 0, stream>>>(ei, cursor);
  scan_blk_kernel<<<98, 256, 0, stream>>>(cursor, row_ptr, blk_sums, N_NODES, N_NODES + 1);
  scan_blk_kernel<<<1, 256, 0, stream>>>(blk_sums, blk_off, nullptr, 98, 98);
  scan_fix_kernel<<<(N_NODES + 256) / 256, 256, 0, stream>>>(row_ptr, blk_off, cursor);
  fill_kernel<<<(E_EDGES + 255) / 256, 256, 0, stream>>>(ei, cursor, csr_src);

  // ---- nodedot[i] = c2 ----
  init_nd_kernel<<<(N_NODES + 255) / 256, 256, 0, stream>>>(nodedot, c2);

  // ---- embed -> H0 (128 wide) ----
  embed_kernel<<<N_NODES / 16, 128, 0, stream>>>(x, W_embed, b_embed, RH);

  const int MB = (N_NODES + 127) / 128;       // 782
  const int MB8 = ((MB + 7) / 8) * 8;         // 784 (padded; tail blocks exit)

  // ---- layer 0: fused gather+GEMM1 (K=128), then GEMM2 ----
  gemm_gather_kernel<128, 1><<<2 * MB8, 256, 0, stream>>>(
      RH, Wt1[0], B1[0], RB, row_ptr, csr_src, eps, 0, N_NODES, 256);
  gemm_kernel<256, 1, 0><<<2 * MB8, 256, 0, stream>>>(RB, Wt2[0], B2[0], RH, nullptr, nullptr, N_NODES, 256);

  // ---- layer 1: fused gather+GEMM1 (K=256), then GEMM2 ----
  gemm_gather_kernel<256, 1><<<2 * MB8, 256, 0, stream>>>(
      RH, Wt1[1], B1[1], RB, row_ptr, csr_src, eps, 1, N_NODES, 256);
  gemm_kernel<256, 1, 0><<<2 * MB8, 256, 0, stream>>>(RB, Wt2[1], B2[1], RH, nullptr, nullptr, N_NODES, 256);

  // ---- layer 2: standalone gather, then MODE-3 GEMM (task-dot fused) ----
  gather_kernel<4><<<N_NODES / 4, 256, 0, stream>>>(RH, RZ, row_ptr, csr_src, eps, 2);
  gemm_kernel<256, 2, 3><<<4 * MB8, 256, 0, stream>>>(RZ, Wt1[2], B1[2], nullptr, w2v, nodedot, N_NODES, 512);

  // ---- out[g] = b_task + segmented sum of nodedot ----
  init_out_kernel<<<(N_GRAPHS + 255) / 256, 256, 0, stream>>>(out, b_task);
  pool_kernel<<<((N_NODES + 63) / 64 + 255) / 256, 256, 0, stream>>>(nodedot, batch, out);
}

// Round 14
// 444.986 us; speedup vs baseline: 1.5626x; 1.5626x over previous
//
#include <hip/hip_runtime.h>

#define N_NODES 100000
#define E_EDGES 300000
#define N_GRAPHS 2048

typedef float  floatx4 __attribute__((ext_vector_type(4)));
typedef short  shortx8 __attribute__((ext_vector_type(8)));

__device__ __forceinline__ float bf2f(unsigned short u) {
  return __uint_as_float(((unsigned int)u) << 16);
}
__device__ __forceinline__ unsigned short f2bf(float f) {
  unsigned int u = __float_as_uint(f);
  u += 0x7FFFu + ((u >> 16) & 1u);
  return (unsigned short)(u >> 16);
}

// async global->LDS, 16B per lane; lds base wave-uniform, dst = base+lane*16 (m104)
__device__ __forceinline__ void cp16(const void* g, void* l) {
  __builtin_amdgcn_global_load_lds(
      (const __attribute__((address_space(1))) unsigned int*)g,
      (__attribute__((address_space(3))) unsigned int*)l, 16, 0, 0);
}

// -------- batched W[k,n] fp32 -> Wt[n,k] bf16 (32x32 LDS tiles, 4 jobs) ------
struct WtJobs {
  const float* W[4];
  unsigned short* Wt[4];
  int K[4];
  int N[4];
};

__global__ __launch_bounds__(256)
void wt4_kernel(WtJobs j) {
  __shared__ unsigned short tile[32][33];
  const int z = blockIdx.z;
  const int K = j.K[z], N = j.N[z];
  const int kb = blockIdx.x * 32, nb = blockIdx.y * 32;
  if (kb >= K || nb >= N) return;
  const float* W = j.W[z];
  unsigned short* Wt = j.Wt[z];
  const int tx = threadIdx.x & 31, ty = threadIdx.x >> 5;
  for (int r = ty; r < 32; r += 8)
    tile[r][tx] = f2bf(W[(size_t)(kb + r) * N + nb + tx]);
  __syncthreads();
  for (int r = ty; r < 32; r += 8)
    Wt[(size_t)(nb + r) * K + kb + tx] = tile[tx][r];
}

// ---- WfT[n*64+k] = bf16((We@W1_0)^T), slot 40 = bv[n] = be@W1_0, 41..63 = 0 --
__global__ __launch_bounds__(256)
void wf_kernel(const float* __restrict__ We, const float* __restrict__ be,
               const float* __restrict__ W1, unsigned short* __restrict__ WfT) {
  const int n = threadIdx.x;  // 0..255
  const int k = blockIdx.x;   // 0..40
  if (k < 40) {
    float s = 0.f;
    for (int j = 0; j < 128; j++) s = fmaf(We[k * 128 + j], W1[(size_t)j * 256 + n], s);
    WfT[n * 64 + k] = f2bf(s);
  } else {
    float s = 0.f;
    for (int j = 0; j < 128; j++) s = fmaf(be[j], W1[(size_t)j * 256 + n], s);
    WfT[n * 64 + 40] = f2bf(s);
    for (int kk = 41; kk < 64; kk++) WfT[n * 64 + kk] = 0;
  }
}

// ---- w2v[k] = sum_n W2_2[k,n]*wtask[n] (wave per k); c2 = b2 . wtask --------
__global__ __launch_bounds__(256)
void w2v_kernel(const float* __restrict__ W2, const float* __restrict__ b2,
                const float* __restrict__ wt, float* __restrict__ w2v,
                float* __restrict__ c2) {
  const int lane = threadIdx.x & 63;
  const int wave = threadIdx.x >> 6;
  if (blockIdx.x < 128) {
    const int k = blockIdx.x * 4 + wave;
    const float* row = W2 + (size_t)k * 512 + lane * 8;
    float4 a0 = *(const float4*)(row);
    float4 a1 = *(const float4*)(row + 4);
    float4 w0 = *(const float4*)(wt + lane * 8);
    float4 w1 = *(const float4*)(wt + lane * 8 + 4);
    float s = a0.x * w0.x + a0.y * w0.y + a0.z * w0.z + a0.w * w0.w +
              a1.x * w1.x + a1.y * w1.y + a1.z * w1.z + a1.w * w1.w;
#pragma unroll
    for (int off = 32; off > 0; off >>= 1) s += __shfl_down(s, off);
    if (lane == 0) w2v[k] = s;
  } else if (wave == 0) {
    float4 a0 = *(const float4*)(b2 + lane * 8);
    float4 a1 = *(const float4*)(b2 + lane * 8 + 4);
    float4 w0 = *(const float4*)(wt + lane * 8);
    float4 w1 = *(const float4*)(wt + lane * 8 + 4);
    float s = a0.x * w0.x + a0.y * w0.y + a0.z * w0.z + a0.w * w0.w +
              a1.x * w1.x + a1.y * w1.y + a1.z * w1.z + a1.w * w1.w;
#pragma unroll
    for (int off = 32; off > 0; off >>= 1) s += __shfl_down(s, off);
    if (lane == 0) *c2 = s;
  }
}

__global__ __launch_bounds__(256)
void init_nd_kernel(float* __restrict__ nd, const float* __restrict__ c2) {
  int i = blockIdx.x * 256 + threadIdx.x;
  if (i < N_NODES) nd[i] = *c2;
}

// ---------------- CSR build: zero, histogram, scan, fill ---------------------
__global__ __launch_bounds__(256)
void zero_kernel(int* __restrict__ p, int n) {
  int i = blockIdx.x * 256 + threadIdx.x;
  if (i < n) p[i] = 0;
}

__global__ __launch_bounds__(256)
void hist_kernel(const int* __restrict__ ei, int* __restrict__ deg) {
  int e = blockIdx.x * 256 + threadIdx.x;
  if (e < E_EDGES) atomicAdd(&deg[ei[E_EDGES + e]], 1);
}

__global__ __launch_bounds__(256)
void scan_blk_kernel(const int* __restrict__ in, int* __restrict__ out,
                     int* __restrict__ blk_sums, int n_in, int n_out) {
  __shared__ int sm[256];
  const int t = threadIdx.x;
  const int base = blockIdx.x * 1024 + t * 4;
  int d0 = (base + 0 < n_in) ? in[base + 0] : 0;
  int d1 = (base + 1 < n_in) ? in[base + 1] : 0;
  int d2 = (base + 2 < n_in) ? in[base + 2] : 0;
  int d3 = (base + 3 < n_in) ? in[base + 3] : 0;
  int s = d0 + d1 + d2 + d3;
  sm[t] = s;
  __syncthreads();
  for (int off = 1; off < 256; off <<= 1) {
    int v = (t >= off) ? sm[t - off] : 0;
    __syncthreads();
    sm[t] += v;
    __syncthreads();
  }
  int excl = sm[t] - s;
  if (base + 0 < n_out) out[base + 0] = excl;
  if (base + 1 < n_out) out[base + 1] = excl + d0;
  if (base + 2 < n_out) out[base + 2] = excl + d0 + d1;
  if (base + 3 < n_out) out[base + 3] = excl + d0 + d1 + d2;
  if (t == 255 && blk_sums) blk_sums[blockIdx.x] = sm[255];
}

__global__ __launch_bounds__(256)
void scan_fix_kernel(int* __restrict__ row_ptr, const int* __restrict__ blk_off,
                     int* __restrict__ cursor) {
  int i = blockIdx.x * 256 + threadIdx.x;
  if (i <= N_NODES) {
    int v = row_ptr[i] + blk_off[i >> 10];
    row_ptr[i] = v;
    if (i < N_NODES) cursor[i] = v;
  }
}

__global__ __launch_bounds__(256)
void fill_kernel(const int* __restrict__ ei, int* __restrict__ cursor,
                 int* __restrict__ csr_src) {
  int e = blockIdx.x * 256 + threadIdx.x;
  if (e < E_EDGES) {
    int d = ei[E_EDGES + e];
    int slot = atomicAdd(&cursor[d], 1);
    csr_src[slot] = ei[e];
  }
}

// ---- gatherx: G[n,64] = bf16([(1+eps)X_n + sum X_src | f_n | 0...]) ---------
// Gather on the 40-wide fp32 X (layer-0 algebraic fold). Slot 40 holds
// f = (1+eps)+deg so the K=64 GEMM against WfT (slot 40 = be@W1) computes
// the bias-embedding term for free. One wave per node.
__global__ __launch_bounds__(256)
void gatherx_kernel(const float* __restrict__ X, unsigned short* __restrict__ G,
                    const int* __restrict__ row_ptr, const int* __restrict__ csr,
                    const float* __restrict__ eps) {
  const int node = blockIdx.x * 4 + (threadIdx.x >> 6);
  const int lane = threadIdx.x & 63;
  const float sc = 1.0f + eps[0];
  const int e0 = row_ptr[node];
  const int e1 = row_ptr[node + 1];
  float acc = 0.f;
  if (lane < 40) {
    acc = sc * X[(size_t)node * 40 + lane];
    for (int e = e0; e < e1; e++)
      acc += X[(size_t)csr[e] * 40 + lane];
  } else if (lane == 40) {
    acc = sc + (float)(e1 - e0);
  }
  G[(size_t)node * 64 + lane] = f2bf(acc);
}

// ------- gather: Z[d] = bf16((1+eps)*H[d] + sum_{s->d} H[s]), fp32 accum -----
template <int NV>  // NV bf16 feats per lane, D = NV*64
__global__ __launch_bounds__(256)
void gather_kernel(const unsigned short* __restrict__ H, unsigned short* __restrict__ Z,
                   const int* __restrict__ row_ptr, const int* __restrict__ csr,
                   const float* __restrict__ eps, int l) {
  const int D = NV * 64;
  const int node = blockIdx.x * 4 + (threadIdx.x >> 6);
  const int lane = threadIdx.x & 63;
  const float sc = 1.0f + eps[l];
  const unsigned short* hp0 = H + (size_t)node * D + lane * NV;
  float acc[NV];
  if constexpr (NV == 4) {
    uint2 hv = *(const uint2*)hp0;
    acc[0] = sc * bf2f((unsigned short)(hv.x & 0xFFFF));
    acc[1] = sc * bf2f((unsigned short)(hv.x >> 16));
    acc[2] = sc * bf2f((unsigned short)(hv.y & 0xFFFF));
    acc[3] = sc * bf2f((unsigned short)(hv.y >> 16));
  } else {
    unsigned int hv = *(const unsigned int*)hp0;
    acc[0] = sc * bf2f((unsigned short)(hv & 0xFFFF));
    acc[1] = sc * bf2f((unsigned short)(hv >> 16));
  }
  const int e0 = row_ptr[node];
  const int e1 = row_ptr[node + 1];
  int e = e0;
  for (; e + 2 <= e1; e += 2) {
    int s0 = csr[e], s1 = csr[e + 1];
    const unsigned short* p0 = H + (size_t)s0 * D + lane * NV;
    const unsigned short* p1 = H + (size_t)s1 * D + lane * NV;
    if constexpr (NV == 4) {
      uint2 a = *(const uint2*)p0;
      uint2 b = *(const uint2*)p1;
      acc[0] += bf2f((unsigned short)(a.x & 0xFFFF)) + bf2f((unsigned short)(b.x & 0xFFFF));
      acc[1] += bf2f((unsigned short)(a.x >> 16))    + bf2f((unsigned short)(b.x >> 16));
      acc[2] += bf2f((unsigned short)(a.y & 0xFFFF)) + bf2f((unsigned short)(b.y & 0xFFFF));
      acc[3] += bf2f((unsigned short)(a.y >> 16))    + bf2f((unsigned short)(b.y >> 16));
    } else {
      unsigned int a = *(const unsigned int*)p0;
      unsigned int b = *(const unsigned int*)p1;
      acc[0] += bf2f((unsigned short)(a & 0xFFFF)) + bf2f((unsigned short)(b & 0xFFFF));
      acc[1] += bf2f((unsigned short)(a >> 16))    + bf2f((unsigned short)(b >> 16));
    }
  }
  if (e < e1) {
    int s0 = csr[e];
    const unsigned short* p0 = H + (size_t)s0 * D + lane * NV;
    if constexpr (NV == 4) {
      uint2 a = *(const uint2*)p0;
      acc[0] += bf2f((unsigned short)(a.x & 0xFFFF));
      acc[1] += bf2f((unsigned short)(a.x >> 16));
      acc[2] += bf2f((unsigned short)(a.y & 0xFFFF));
      acc[3] += bf2f((unsigned short)(a.y >> 16));
    } else {
      unsigned int a = *(const unsigned int*)p0;
      acc[0] += bf2f((unsigned short)(a & 0xFFFF));
      acc[1] += bf2f((unsigned short)(a >> 16));
    }
  }
  unsigned short* zp = Z + (size_t)node * D + lane * NV;
  if constexpr (NV == 4) {
    unsigned short z[4] = {f2bf(acc[0]), f2bf(acc[1]), f2bf(acc[2]), f2bf(acc[3])};
    *(uint2*)zp = *(uint2*)z;
  } else {
    unsigned short z[2] = {f2bf(acc[0]), f2bf(acc[1])};
    *(unsigned int*)zp = *(unsigned int*)z;
  }
}

// ---- GEMM (R11): act(A @ Bt^T + bias), 128x128 tile, BK=64, 4 waves --------
// XOR swizzle (zero conflicts) + LDS-staged epilogue (full-line C stores) +
// XCD block swizzle (column blocks 8 IDs apart share an XCD -> A L2 reuse).
// MODE 0: C = bf16(relu(.)). MODE 3: nodedot[row] += sum relu(.)*w2v[col].
template <int K, int NXL, int MODE>
__global__ __launch_bounds__(256)
void gemm_kernel(const unsigned short* __restrict__ A,
                 const unsigned short* __restrict__ Bt,
                 const float* __restrict__ bias, unsigned short* __restrict__ C,
                 const float* __restrict__ w2v, float* __restrict__ nodedot,
                 int M, int N) {
  const int g = blockIdx.x;
  const int mblk = ((g >> (3 + NXL)) << 3) | (g & 7);
  const int nblk = (g >> 3) & ((1 << NXL) - 1);
  const int m0 = mblk * 128;
  const int n0 = nblk * 128;
  if (m0 >= M) return;

  __shared__ unsigned short smem[2 * 128 * 64];  // 32 KB: As+Bs, reused as C-tile
  unsigned short* As = smem;
  unsigned short* Bs = smem + 128 * 64;
  const int tid = threadIdx.x;
  const int lane = tid & 63;
  const int wave = tid >> 6;
  const int wm = (wave & 1) * 64;
  const int wn = (wave >> 1) * 64;
  const int fr = lane & 15;
  const int fq = lane >> 4;

  floatx4 acc[4][4];
#pragma unroll
  for (int i = 0; i < 4; i++)
#pragma unroll
    for (int j = 0; j < 4; j++) acc[i][j] = (floatx4){0.f, 0.f, 0.f, 0.f};

  const unsigned short* gA[4];
  const unsigned short* gB[4];
  unsigned short* lA[4];
  unsigned short* lB[4];
#pragma unroll
  for (int p = 0; p < 4; p++) {
    int c = p * 256 + wave * 64 + lane;
    int row = c >> 3;
    int q = (c & 7) ^ (row & 7);
    int grA = m0 + row;
    if (grA >= M) grA = M - 1;
    gA[p] = A + (size_t)grA * K + q * 8;
    gB[p] = Bt + (size_t)(n0 + row) * K + q * 8;
    lA[p] = &As[(p * 256 + wave * 64) * 8];
    lB[p] = &Bs[(p * 256 + wave * 64) * 8];
  }

  for (int k0 = 0; k0 < K; k0 += 64) {
#pragma unroll
    for (int p = 0; p < 4; p++) cp16(gA[p] + k0, lA[p]);
#pragma unroll
    for (int p = 0; p < 4; p++) cp16(gB[p] + k0, lB[p]);
    __syncthreads();
#pragma unroll
    for (int s0 = 0; s0 < 2; s0++) {
      shortx8 af[4], bf[4];
#pragma unroll
      for (int i = 0; i < 4; i++)
        af[i] = *(const shortx8*)&As[(wm + i * 16 + fr) * 64 +
                                     (((s0 * 4 + fq) ^ (fr & 7)) * 8)];
#pragma unroll
      for (int j = 0; j < 4; j++)
        bf[j] = *(const shortx8*)&Bs[(wn + j * 16 + fr) * 64 +
                                     (((s0 * 4 + fq) ^ (fr & 7)) * 8)];
#pragma unroll
      for (int i = 0; i < 4; i++)
#pragma unroll
        for (int j = 0; j < 4; j++)
          acc[i][j] = __builtin_amdgcn_mfma_f32_16x16x32_bf16(af[i], bf[j], acc[i][j], 0, 0, 0);
    }
    __syncthreads();
  }

  if (MODE == 3) {
    float wv[4], bj[4];
#pragma unroll
    for (int j = 0; j < 4; j++) {
      int col = n0 + wn + j * 16 + fr;
      wv[j] = w2v[col];
      bj[j] = bias[col];
    }
#pragma unroll
    for (int i = 0; i < 4; i++) {
#pragma unroll
      for (int r = 0; r < 4; r++) {
        float p = 0.f;
#pragma unroll
        for (int j = 0; j < 4; j++) p += fmaxf(acc[i][j][r] + bj[j], 0.f) * wv[j];
#pragma unroll
        for (int off = 1; off < 16; off <<= 1) p += __shfl_xor(p, off);
        if (fr == 0) {
          int row = m0 + wm + i * 16 + fq * 4 + r;
          if (row < M) unsafeAtomicAdd(&nodedot[row], p);
        }
      }
    }
  } else {
    unsigned short* Cs = smem;
#pragma unroll
    for (int j = 0; j < 4; j++) {
      int col = wn + j * 16 + fr;
      float bj = bias[n0 + col];
#pragma unroll
      for (int i = 0; i < 4; i++) {
#pragma unroll
        for (int r = 0; r < 4; r++) {
          int row = wm + i * 16 + fq * 4 + r;
          Cs[row * 128 + col] = f2bf(fmaxf(acc[i][j][r] + bj, 0.f));
        }
      }
    }
    __syncthreads();
    const int rcol = (tid & 15) * 8;
#pragma unroll
    for (int p = 0; p < 8; p++) {
      int row = p * 16 + (tid >> 4);
      int grow = m0 + row;
      if (grow < M) {
        uint4 v = *(const uint4*)&Cs[row * 128 + rcol];
        *(uint4*)&C[(size_t)grow * N + n0 + rcol] = v;
      }
    }
  }
}

// ---------------- readout ----------------------------------------------------
__global__ __launch_bounds__(256)
void init_out_kernel(float* __restrict__ out, const float* __restrict__ b_task) {
  int g = blockIdx.x * 256 + threadIdx.x;
  if (g < N_GRAPHS) out[g] = b_task[0];
}

__global__ __launch_bounds__(256)
void pool_kernel(const float* __restrict__ nodedot, const int* __restrict__ batch,
                 float* __restrict__ out) {
  int t = blockIdx.x * 256 + threadIdx.x;
  int i0 = t * 64;
  if (i0 >= N_NODES) return;
  int i1 = i0 + 64;
  if (i1 > N_NODES) i1 = N_NODES;
  int g = batch[i0];
  float s = 0.f;
  for (int i = i0; i < i1; i++) {
    int gi = batch[i];
    if (gi != g) { unsafeAtomicAdd(&out[g], s); g = gi; s = 0.f; }
    s += nodedot[i];
  }
  unsafeAtomicAdd(&out[g], s);
}

extern "C" void kernel_launch(void* const* d_in, const int* in_sizes, int n_in,
                              void* d_out, int out_size, void* d_ws, size_t ws_size,
                              hipStream_t stream) {
  const float* x       = (const float*)d_in[0];
  const int*   ei      = (const int*)d_in[1];
  const int*   batch   = (const int*)d_in[2];
  const float* W_embed = (const float*)d_in[3];
  const float* b_embed = (const float*)d_in[4];
  const float* eps     = (const float*)d_in[5];
  const float* W1[3] = {(const float*)d_in[6],  (const float*)d_in[10], (const float*)d_in[14]};
  const float* B1[3] = {(const float*)d_in[7],  (const float*)d_in[11], (const float*)d_in[15]};
  const float* W2[3] = {(const float*)d_in[8],  (const float*)d_in[12], (const float*)d_in[16]};
  const float* B2[3] = {(const float*)d_in[9],  (const float*)d_in[13], (const float*)d_in[17]};
  const float* W_task = (const float*)d_in[18];
  const float* b_task = (const float*)d_in[19];
  float* out = (float*)d_out;

  const size_t OFF_RB  = 51200000;
  const size_t OFF_RZ  = 102400000;
  const size_t OFF_AUX = 153600000;
  if (ws_size < OFF_AUX + 4000000) return;
  unsigned short* RH = (unsigned short*)d_ws;
  unsigned short* RB = (unsigned short*)((char*)d_ws + OFF_RB);
  unsigned short* RZ = (unsigned short*)((char*)d_ws + OFF_RZ);
  char* aux = (char*)d_ws + OFF_AUX;
  int* row_ptr  = (int*)(aux);               // 100001 ints
  int* cursor   = (int*)(aux + 400016);      // 100000 ints (also deg histogram)
  int* csr_src  = (int*)(aux + 800016);      // 300000 ints
  int* blk_sums = (int*)(aux + 2000016);     // 98 ints
  int* blk_off  = (int*)(aux + 2000416);     // 98 ints
  float* nodedot = (float*)(aux + 2000816);  // 100000 floats
  unsigned short* WT = (unsigned short*)(aux + 2400832);  // 360448 bf16
  float* w2v = (float*)(aux + 3200832);      // 512 floats
  float* c2  = (float*)(aux + 3202880);      // 1 float
  // slot 0 (was Wt1[0], 32768 elems) now holds WfT (256*64 = 16384 elems)
  unsigned short* WfT    = WT;
  unsigned short* Wt2_0  = WT + 32768;
  unsigned short* Wt1_1  = WT + 98304;
  unsigned short* Wt2_1  = WT + 163840;
  unsigned short* Wt1_2  = WT + 229376;

  // ---- weight transpose+convert (4 jobs, one dispatch) ----
  WtJobs jobs;
  jobs.W[0] = W2[0]; jobs.Wt[0] = Wt2_0; jobs.K[0] = 256; jobs.N[0] = 256;
  jobs.W[1] = W1[1]; jobs.Wt[1] = Wt1_1; jobs.K[1] = 256; jobs.N[1] = 256;
  jobs.W[2] = W2[1]; jobs.Wt[2] = Wt2_1; jobs.K[2] = 256; jobs.N[2] = 256;
  jobs.W[3] = W1[2]; jobs.Wt[3] = Wt1_2; jobs.K[3] = 256; jobs.N[3] = 512;
  wt4_kernel<<<dim3(8, 16, 4), 256, 0, stream>>>(jobs);

  // ---- WfT = (We @ W1_0)^T (+ bv in slot 40); w2v = W2_2 @ w_task ----
  wf_kernel<<<41, 256, 0, stream>>>(W_embed, b_embed, W1[0], WfT);
  w2v_kernel<<<129, 256, 0, stream>>>(W2[2], B2[2], W_task, w2v, c2);

  // ---- CSR build ----
  zero_kernel<<<(N_NODES + 255) / 256, 256, 0, stream>>>(cursor, N_NODES);
  hist_kernel<<<(E_EDGES + 255) / 256, 256, 0, stream>>>(ei, cursor);
  scan_blk_kernel<<<98, 256, 0, stream>>>(cursor, row_ptr, blk_sums, N_NODES, N_NODES + 1);
  scan_blk_kernel<<<1, 256, 0, stream>>>(blk_sums, blk_off, nullptr, 98, 98);
  scan_fix_kernel<<<(N_NODES + 256) / 256, 256, 0, stream>>>(row_ptr, blk_off, cursor);
  fill_kernel<<<(E_EDGES + 255) / 256, 256, 0, stream>>>(ei, cursor, csr_src);

  // ---- nodedot[i] = c2 ----
  init_nd_kernel<<<(N_NODES + 255) / 256, 256, 0, stream>>>(nodedot, c2);

  const int MB = (N_NODES + 127) / 128;       // 782
  const int MB8 = ((MB + 7) / 8) * 8;         // 784 (padded; tail blocks exit)

  // ---- layer 0 (folded): G = gather(X)+deg-slot -> T0 = relu(G@WfT^T + b1) --
  gatherx_kernel<<<N_NODES / 4, 256, 0, stream>>>(x, RZ, row_ptr, csr_src, eps);
  gemm_kernel<64, 1, 0><<<2 * MB8, 256, 0, stream>>>(RZ, WfT, B1[0], RB, nullptr, nullptr, N_NODES, 256);
  gemm_kernel<256, 1, 0><<<2 * MB8, 256, 0, stream>>>(RB, Wt2_0, B2[0], RH, nullptr, nullptr, N_NODES, 256);

  // ---- layer 1 ----
  gather_kernel<4><<<N_NODES / 4, 256, 0, stream>>>(RH, RZ, row_ptr, csr_src, eps, 1);
  gemm_kernel<256, 1, 0><<<2 * MB8, 256, 0, stream>>>(RZ, Wt1_1, B1[1], RB, nullptr, nullptr, N_NODES, 256);
  gemm_kernel<256, 1, 0><<<2 * MB8, 256, 0, stream>>>(RB, Wt2_1, B2[1], RH, nullptr, nullptr, N_NODES, 256);

  // ---- layer 2: gather, then MODE-3 GEMM (task-dot fused) ----
  gather_kernel<4><<<N_NODES / 4, 256, 0, stream>>>(RH, RZ, row_ptr, csr_src, eps, 2);
  gemm_kernel<256, 2, 3><<<4 * MB8, 256, 0, stream>>>(RZ, Wt1_2, B1[2], nullptr, w2v, nodedot, N_NODES, 512);

  // ---- out[g] = b_task + segmented sum of nodedot ----
  init_out_kernel<<<(N_GRAPHS + 255) / 256, 256, 0, stream>>>(out, b_task);
  pool_kernel<<<((N_NODES + 63) / 64 + 255) / 256, 256, 0, stream>>>(nodedot, batch, out);
}